// Round 9
// baseline (50.645 us; speedup 1.0000x reference)
//
#include <hip/hip_runtime.h>
#include <math.h>

#define N       8192
#define BLK     256
#define JCHUNK  256                  // B-points per block (one slice)
#define NSLICE  (N / JCHUNK)         // 32
#define ITILES  (N / BLK)            // 32
#define HALF    (ITILES * NSLICE)    // 1024 blocks per direction
#define GRID    (2 * HALF)           // 2048 = 8 blocks/CU, 32 waves/CU

// ---------------------------------------------------- precompute + init ----
// P[0..N) = target packed {x,y,z,|p|^2}; P[N..2N) = output packed.
// dmin[0..2N) = +inf bits; cnt = 0 (reset every call -- graph replay safe).
__global__ __launch_bounds__(BLK) void chamfer_prep_kernel(
        const float* __restrict__ tgt, const float* __restrict__ outp,
        float4* __restrict__ P, unsigned* __restrict__ dmin,
        unsigned* __restrict__ cnt) {
    int i = blockIdx.x * BLK + (int)threadIdx.x;   // 0 .. 2N-1
    if (i == 0) cnt[0] = 0u;
    const float* src = (i < N) ? tgt : outp;
    int k = (i < N) ? i : (i - N);
    float x = src[3 * k + 0];
    float y = src[3 * k + 1];
    float z = src[3 * k + 2];
    P[i] = make_float4(x, y, z, fmaf(x, x, fmaf(y, y, z * z)));
    dmin[i] = 0x7F800000u;  // +inf
}

// ---------------------------------------------------------------- dist ----
// R8 structure + (a) v_min3 epilogue per point-pair (fminf(fminf(m,u),v)
// fuses to v_min3_f32 -- merges the two load-streams' mins), (b) fused
// last-block sqrt-mean reduction with NO fence: only s_waitcnt vmcnt(0)
// before the completion-counter bump. Device-scope atomics + agent-scope
// atomic loads all meet at the L2-bypassing coherence point (protocol
// proven correct in R4-R7; the __threadfence was the 113us poison).
__global__ __launch_bounds__(BLK) void chamfer_dist_kernel(
        const float4* __restrict__ P, unsigned* __restrict__ dmin,
        unsigned* __restrict__ cnt,
        const int* __restrict__ curp, const int* __restrict__ subp,
        float* __restrict__ out) {
    __shared__ int   lastf;
    __shared__ float red1[BLK / 64], red2[BLK / 64];

    int tid = (int)threadIdx.x;
    int bid = (int)blockIdx.x;
    int dir = (bid >= HALF) ? 1 : 0;
    if (dir) bid -= HALF;
    int aoff = dir ? N : 0;
    int boff = dir ? 0 : N;

    int itile = bid / NSLICE;
    int slice = bid % NSLICE;
    int i = itile * BLK + tid;

    float4 a = P[aoff + i];
    float axm = -2.0f * a.x;
    float aym = -2.0f * a.y;
    float azm = -2.0f * a.z;

    const float inf = __builtin_inff();
    float m0 = inf, m1 = inf, m2 = inf, m3 = inf;

    const float4* __restrict__ bp = P + boff + slice * JCHUNK;  // wave-uniform
    #pragma unroll 4
    for (int j = 0; j < JCHUNK / 2; j += 4) {
        float4 b0 = bp[j + 0];
        float4 b1 = bp[j + 1];
        float4 b2 = bp[j + 2];
        float4 b3 = bp[j + 3];
        float4 c0 = bp[j + 128];
        float4 c1 = bp[j + 129];
        float4 c2 = bp[j + 130];
        float4 c3 = bp[j + 131];
        float ub0 = fmaf(axm, b0.x, fmaf(aym, b0.y, fmaf(azm, b0.z, b0.w)));
        float ub1 = fmaf(axm, b1.x, fmaf(aym, b1.y, fmaf(azm, b1.z, b1.w)));
        float ub2 = fmaf(axm, b2.x, fmaf(aym, b2.y, fmaf(azm, b2.z, b2.w)));
        float ub3 = fmaf(axm, b3.x, fmaf(aym, b3.y, fmaf(azm, b3.z, b3.w)));
        float uc0 = fmaf(axm, c0.x, fmaf(aym, c0.y, fmaf(azm, c0.z, c0.w)));
        float uc1 = fmaf(axm, c1.x, fmaf(aym, c1.y, fmaf(azm, c1.z, c1.w)));
        float uc2 = fmaf(axm, c2.x, fmaf(aym, c2.y, fmaf(azm, c2.z, c2.w)));
        float uc3 = fmaf(axm, c3.x, fmaf(aym, c3.y, fmaf(azm, c3.z, c3.w)));
        m0 = fminf(fminf(m0, ub0), uc0);   // -> v_min3_f32
        m1 = fminf(fminf(m1, ub1), uc1);
        m2 = fminf(fminf(m2, ub2), uc2);
        m3 = fminf(fminf(m3, ub3), uc3);
    }
    float m = fminf(fminf(m0, m1), fminf(m2, m3));
    float d2 = fmaxf(a.w + m, 0.0f);
    atomicMin(&dmin[aoff + i], __float_as_uint(d2));   // coalesced, 1/thread

    // ---- completion counter: waitcnt only, NO cache-flushing fence ----
    asm volatile("s_waitcnt vmcnt(0)" ::: "memory");
    if (tid == 0)
        lastf = (__hip_atomic_fetch_add(cnt, 1u, __ATOMIC_RELAXED,
                                        __HIP_MEMORY_SCOPE_AGENT)
                 == (unsigned)(GRID - 1));
    __syncthreads();
    if (!lastf) return;

    // ---- last block: sqrt-mean reduction via L2-bypassing atomic loads ----
    int wid = tid >> 6, lane = tid & 63;
    float s1 = 0.0f, s2 = 0.0f;
    for (int t = tid; t < N; t += BLK) {
        unsigned u1 = __hip_atomic_load(&dmin[t],     __ATOMIC_RELAXED, __HIP_MEMORY_SCOPE_AGENT);
        unsigned u2 = __hip_atomic_load(&dmin[N + t], __ATOMIC_RELAXED, __HIP_MEMORY_SCOPE_AGENT);
        s1 += sqrtf(__uint_as_float(u1));
        s2 += sqrtf(__uint_as_float(u2));
    }
    #pragma unroll
    for (int off = 32; off > 0; off >>= 1) {
        s1 += __shfl_down(s1, off, 64);
        s2 += __shfl_down(s2, off, 64);
    }
    if (lane == 0) { red1[wid] = s1; red2[wid] = s2; }
    __syncthreads();
    if (tid == 0) {
        float t1 = 0.0f, t2 = 0.0f;
        #pragma unroll
        for (int w = 0; w < BLK / 64; ++w) { t1 += red1[w]; t2 += red2[w]; }
        int e = curp[0] / subp[0];
        double scale = 10.0 / pow(0.99, (double)e);
        out[0] = (float)((((double)t1 + (double)t2) / (double)N) * 0.5 * scale);
    }
}

// ---------------------------------------------------------------- launch ----
extern "C" void kernel_launch(void* const* d_in, const int* in_sizes, int n_in,
                              void* d_out, int out_size, void* d_ws, size_t ws_size,
                              hipStream_t stream) {
    const float* target = (const float*)d_in[0];   // (1, 8192, 3) f32
    const float* output = (const float*)d_in[1];   // (1, 8192, 3) f32
    const int*   curp   = (const int*)d_in[2];
    const int*   subp   = (const int*)d_in[3];
    float* out = (float*)d_out;

    // ws: float4 P[2N] (256 KB) | uint dmin[2N] (64 KB) | uint cnt
    float4*   P    = (float4*)d_ws;
    unsigned* dmin = (unsigned*)(P + 2 * N);
    unsigned* cnt  = dmin + 2 * N;

    chamfer_prep_kernel<<<2 * N / BLK, BLK, 0, stream>>>(target, output, P, dmin, cnt);
    chamfer_dist_kernel<<<GRID, BLK, 0, stream>>>(P, dmin, cnt, curp, subp, out);
}

// Round 10
// 27.427 us; speedup vs baseline: 1.8466x; 1.8466x over previous
//
#include <hip/hip_runtime.h>
#include <math.h>

#define N       8192
#define BLK     256
#define JCHUNK  256                  // B-points per block (one slice)
#define NSLICE  (N / JCHUNK)         // 32
#define ITILES  (N / BLK)            // 32
#define HALF    (ITILES * NSLICE)    // 1024 blocks per direction
#define GRID    (2 * HALF)           // 2048 = 8 blocks/CU, 32 waves/CU
#define RBLK    1024

typedef float v2f __attribute__((ext_vector_type(2)));

// ---------------------------------------------------- precompute + init ----
// P[0..N) = target {x,y,z,|p|^2}, P[N..2N) = output  (A-role, float4 AoS).
// Ppk: pair-transposed B-role layout, per point-pair group of 8 floats:
//   [x0 x1 y0 y1 z0 z1 w0 w1]  -> v2f lanes line up for v_pk_fma_f32.
//   target groups at float offset 0, output groups at 4N.
// dmin[0..2N) = +inf bits.
__global__ __launch_bounds__(BLK) void chamfer_prep_kernel(
        const float* __restrict__ tgt, const float* __restrict__ outp,
        float4* __restrict__ P, float* __restrict__ Ppk,
        unsigned* __restrict__ dmin) {
    int i = blockIdx.x * BLK + (int)threadIdx.x;   // 0 .. 2N-1
    const float* src = (i < N) ? tgt : outp;
    int k = (i < N) ? i : (i - N);
    float x = src[3 * k + 0];
    float y = src[3 * k + 1];
    float z = src[3 * k + 2];
    float n2 = fmaf(x, x, fmaf(y, y, z * z));
    P[i] = make_float4(x, y, z, n2);

    int cbase = (i < N) ? 0 : 4 * N;       // cloud base (floats)
    int g = k >> 1, e = k & 1;
    float* q = Ppk + cbase + 8 * g + e;
    q[0] = x; q[2] = y; q[4] = z; q[6] = n2;

    dmin[i] = 0x7F800000u;  // +inf
}

// ---------------------------------------------------------------- dist ----
// R8 3-kernel structure (best: 31.5us). ONE change: packed-fp32 inner loop.
// Per point-pair group: u = pk_fma(axm,X, pk_fma(aym,Y, pk_fma(azm,Z,W)))
// then m = min3(m, u.x, u.y). ~2 VALU inst/pair (vs ~5 scalar).
// d^2 = |a|^2 + (|b|^2 - 2 a.b); |a|^2 commutes with min.
__global__ __launch_bounds__(BLK) void chamfer_dist_kernel(
        const float4* __restrict__ P, const v2f* __restrict__ Ppk,
        unsigned* __restrict__ dmin) {
    int tid = (int)threadIdx.x;
    int bid = (int)blockIdx.x;
    int dir = (bid >= HALF) ? 1 : 0;
    if (dir) bid -= HALF;
    int aoff = dir ? N : 0;                 // A-role cloud (float4 index)
    int bpk  = dir ? 0 : 2 * N;             // B-role cloud base (v2f index)

    int itile = bid / NSLICE;
    int slice = bid % NSLICE;
    int i = itile * BLK + tid;

    float4 a = P[aoff + i];
    float nx = -2.0f * a.x, ny = -2.0f * a.y, nz = -2.0f * a.z;
    v2f axm = {nx, nx};
    v2f aym = {ny, ny};
    v2f azm = {nz, nz};

    const float inf = __builtin_inff();
    float m0 = inf, m1 = inf, m2 = inf, m3 = inf;

    // slice start: point j0 = slice*JCHUNK -> group g0 = j0/2, 4 v2f per group
    const v2f* __restrict__ bp = Ppk + bpk + (size_t)slice * (JCHUNK * 2);  // wave-uniform

    #pragma unroll 4
    for (int g = 0; g < JCHUNK / 2; g += 4) {           // 4 pair-groups = 8 pts
        const v2f* q = bp + g * 4;
        v2f X0 = q[0],  Y0 = q[1],  Z0 = q[2],  W0 = q[3];
        v2f X1 = q[4],  Y1 = q[5],  Z1 = q[6],  W1 = q[7];
        v2f X2 = q[8],  Y2 = q[9],  Z2 = q[10], W2 = q[11];
        v2f X3 = q[12], Y3 = q[13], Z3 = q[14], W3 = q[15];
        v2f u0 = __builtin_elementwise_fma(axm, X0,
                 __builtin_elementwise_fma(aym, Y0,
                 __builtin_elementwise_fma(azm, Z0, W0)));
        v2f u1 = __builtin_elementwise_fma(axm, X1,
                 __builtin_elementwise_fma(aym, Y1,
                 __builtin_elementwise_fma(azm, Z1, W1)));
        v2f u2 = __builtin_elementwise_fma(axm, X2,
                 __builtin_elementwise_fma(aym, Y2,
                 __builtin_elementwise_fma(azm, Z2, W2)));
        v2f u3 = __builtin_elementwise_fma(axm, X3,
                 __builtin_elementwise_fma(aym, Y3,
                 __builtin_elementwise_fma(azm, Z3, W3)));
        m0 = fminf(fminf(m0, u0.x), u0.y);   // -> v_min3_f32
        m1 = fminf(fminf(m1, u1.x), u1.y);
        m2 = fminf(fminf(m2, u2.x), u2.y);
        m3 = fminf(fminf(m3, u3.x), u3.y);
    }
    float m = fminf(fminf(m0, m1), fminf(m2, m3));
    float d2 = fmaxf(a.w + m, 0.0f);
    atomicMin(&dmin[aoff + i], __float_as_uint(d2));   // coalesced, 1/thread
}

// -------------------------------------------------------------- reduce ----
__global__ __launch_bounds__(RBLK) void chamfer_reduce_kernel(
        const unsigned* __restrict__ dmin,
        const int* __restrict__ curp, const int* __restrict__ subp,
        float* __restrict__ out) {
    __shared__ float sh1[RBLK / 64], sh2[RBLK / 64];
    int t = (int)threadIdx.x;
    float s1 = 0.0f, s2 = 0.0f;
    const uint4* da = (const uint4*)dmin;          // dist1 as uint4
    const uint4* db = (const uint4*)(dmin + N);    // dist2 as uint4
    for (int i = t; i < N / 4; i += RBLK) {
        uint4 v1 = da[i], v2 = db[i];
        s1 += sqrtf(__uint_as_float(v1.x)) + sqrtf(__uint_as_float(v1.y))
            + sqrtf(__uint_as_float(v1.z)) + sqrtf(__uint_as_float(v1.w));
        s2 += sqrtf(__uint_as_float(v2.x)) + sqrtf(__uint_as_float(v2.y))
            + sqrtf(__uint_as_float(v2.z)) + sqrtf(__uint_as_float(v2.w));
    }
    #pragma unroll
    for (int off = 32; off > 0; off >>= 1) {
        s1 += __shfl_down(s1, off, 64);
        s2 += __shfl_down(s2, off, 64);
    }
    int wid = t >> 6, lane = t & 63;
    if (lane == 0) { sh1[wid] = s1; sh2[wid] = s2; }
    __syncthreads();
    if (t == 0) {
        float t1 = 0.0f, t2 = 0.0f;
        #pragma unroll
        for (int w = 0; w < RBLK / 64; ++w) { t1 += sh1[w]; t2 += sh2[w]; }
        int e = curp[0] / subp[0];
        double scale = 10.0 / pow(0.99, (double)e);
        out[0] = (float)((((double)t1 + (double)t2) / (double)N) * 0.5 * scale);
    }
}

// ---------------------------------------------------------------- launch ----
extern "C" void kernel_launch(void* const* d_in, const int* in_sizes, int n_in,
                              void* d_out, int out_size, void* d_ws, size_t ws_size,
                              hipStream_t stream) {
    const float* target = (const float*)d_in[0];   // (1, 8192, 3) f32
    const float* output = (const float*)d_in[1];   // (1, 8192, 3) f32
    const int*   curp   = (const int*)d_in[2];
    const int*   subp   = (const int*)d_in[3];
    float* out = (float*)d_out;

    // ws: float4 P[2N] (256KB) | float Ppk[8N] (256KB) | uint dmin[2N] (64KB)
    float4*   P    = (float4*)d_ws;
    float*    Ppk  = (float*)(P + 2 * N);
    unsigned* dmin = (unsigned*)(Ppk + 8 * N);

    chamfer_prep_kernel<<<2 * N / BLK, BLK, 0, stream>>>(target, output, P, Ppk, dmin);
    chamfer_dist_kernel<<<GRID, BLK, 0, stream>>>(P, (const v2f*)Ppk, dmin);
    chamfer_reduce_kernel<<<1, RBLK, 0, stream>>>(dmin, curp, subp, out);
}

// Round 11
// 25.704 us; speedup vs baseline: 1.9704x; 1.0670x over previous
//
#include <hip/hip_runtime.h>
#include <math.h>

#define N        8192
#define BLK      256
#define RPT      2                    // a-points (rows) per thread
#define ROWS_BLK (BLK * RPT)          // 512 rows per block
#define ITILES   (N / ROWS_BLK)       // 16
#define NSLICE   64                   // j-slices per direction
#define JCHUNK   (N / NSLICE)         // 128 b-points per slice
#define HALF     (ITILES * NSLICE)    // 1024 blocks per direction
#define GRID     (2 * HALF)           // 2048 = 8 blocks/CU, 32 waves/CU
#define RBLK     1024

typedef float v2f __attribute__((ext_vector_type(2)));

// ---------------------------------------------------- precompute + init ----
// P[0..N) = target {x,y,z,|p|^2}, P[N..2N) = output  (A-role, float4 AoS).
// Ppk: pair-transposed B-role layout, per point-pair group of 8 floats:
//   [x0 x1 y0 y1 z0 z1 w0 w1] -> v2f lanes line up for v_pk_fma_f32.
//   target groups at float offset 0, output groups at 4N.
// dmin[0..2N) = +inf bits.
__global__ __launch_bounds__(BLK) void chamfer_prep_kernel(
        const float* __restrict__ tgt, const float* __restrict__ outp,
        float4* __restrict__ P, float* __restrict__ Ppk,
        unsigned* __restrict__ dmin) {
    int i = blockIdx.x * BLK + (int)threadIdx.x;   // 0 .. 2N-1
    const float* src = (i < N) ? tgt : outp;
    int k = (i < N) ? i : (i - N);
    float x = src[3 * k + 0];
    float y = src[3 * k + 1];
    float z = src[3 * k + 2];
    float n2 = fmaf(x, x, fmaf(y, y, z * z));
    P[i] = make_float4(x, y, z, n2);

    int cbase = (i < N) ? 0 : 4 * N;       // cloud base (floats)
    int g = k >> 1, e = k & 1;
    float* q = Ppk + cbase + 8 * g + e;
    q[0] = x; q[2] = y; q[4] = z; q[6] = n2;

    dmin[i] = 0x7F800000u;  // +inf
}

// ---------------------------------------------------------------- dist ----
// R10 packed loop (2 VALU inst/pair: pk_fma x3 per 2 points + min3) with
// RPT=2: each thread owns TWO a-points (rows i and i+256), so each scalar
// B-fetch feeds both rows -> total scalar-pipe traffic halves (32MB->16MB)
// at full occupancy (GRID=2048). Atomics double to 1M (64KB target, ok).
// d^2 = |a|^2 + (|b|^2 - 2 a.b); |a|^2 commutes with min.
__global__ __launch_bounds__(BLK) void chamfer_dist_kernel(
        const float4* __restrict__ P, const v2f* __restrict__ Ppk,
        unsigned* __restrict__ dmin) {
    int tid = (int)threadIdx.x;
    int bid = (int)blockIdx.x;
    int dir = (bid >= HALF) ? 1 : 0;
    if (dir) bid -= HALF;
    int aoff = dir ? N : 0;                 // A-role cloud (float4 index)
    int bpk  = dir ? 0 : 2 * N;             // B-role cloud base (v2f index)

    int itile = bid / NSLICE;
    int slice = bid % NSLICE;
    int i = itile * ROWS_BLK + tid;         // rows i and i+BLK

    float4 a0 = P[aoff + i];
    float4 a1 = P[aoff + i + BLK];
    float n0x = -2.0f * a0.x, n0y = -2.0f * a0.y, n0z = -2.0f * a0.z;
    float n1x = -2.0f * a1.x, n1y = -2.0f * a1.y, n1z = -2.0f * a1.z;
    v2f ax0 = {n0x, n0x}, ay0 = {n0y, n0y}, az0 = {n0z, n0z};
    v2f ax1 = {n1x, n1x}, ay1 = {n1y, n1y}, az1 = {n1z, n1z};

    const float inf = __builtin_inff();
    float m00 = inf, m01 = inf;   // row 0 accumulators
    float m10 = inf, m11 = inf;   // row 1 accumulators

    // slice covers points [slice*JCHUNK, +JCHUNK) = JCHUNK/2 pair-groups,
    // 4 v2f per group -> v2f offset slice*(JCHUNK*2). Wave-uniform.
    const v2f* __restrict__ bp = Ppk + bpk + (size_t)slice * (JCHUNK * 2);

    #pragma unroll 2
    for (int g = 0; g < JCHUNK / 2; g += 2) {           // 2 pair-groups = 4 pts
        const v2f* q = bp + g * 4;
        v2f X0 = q[0], Y0 = q[1], Z0 = q[2], W0 = q[3];
        v2f X1 = q[4], Y1 = q[5], Z1 = q[6], W1 = q[7];
        v2f u00 = __builtin_elementwise_fma(ax0, X0,
                  __builtin_elementwise_fma(ay0, Y0,
                  __builtin_elementwise_fma(az0, Z0, W0)));
        v2f u01 = __builtin_elementwise_fma(ax0, X1,
                  __builtin_elementwise_fma(ay0, Y1,
                  __builtin_elementwise_fma(az0, Z1, W1)));
        v2f u10 = __builtin_elementwise_fma(ax1, X0,
                  __builtin_elementwise_fma(ay1, Y0,
                  __builtin_elementwise_fma(az1, Z0, W0)));
        v2f u11 = __builtin_elementwise_fma(ax1, X1,
                  __builtin_elementwise_fma(ay1, Y1,
                  __builtin_elementwise_fma(az1, Z1, W1)));
        m00 = fminf(fminf(m00, u00.x), u00.y);   // -> v_min3_f32
        m01 = fminf(fminf(m01, u01.x), u01.y);
        m10 = fminf(fminf(m10, u10.x), u10.y);
        m11 = fminf(fminf(m11, u11.x), u11.y);
    }
    float d20 = fmaxf(a0.w + fminf(m00, m01), 0.0f);
    float d21 = fmaxf(a1.w + fminf(m10, m11), 0.0f);
    atomicMin(&dmin[aoff + i],       __float_as_uint(d20));   // coalesced
    atomicMin(&dmin[aoff + i + BLK], __float_as_uint(d21));   // coalesced
}

// -------------------------------------------------------------- reduce ----
__global__ __launch_bounds__(RBLK) void chamfer_reduce_kernel(
        const unsigned* __restrict__ dmin,
        const int* __restrict__ curp, const int* __restrict__ subp,
        float* __restrict__ out) {
    __shared__ float sh1[RBLK / 64], sh2[RBLK / 64];
    int t = (int)threadIdx.x;
    float s1 = 0.0f, s2 = 0.0f;
    const uint4* da = (const uint4*)dmin;          // dist1 as uint4
    const uint4* db = (const uint4*)(dmin + N);    // dist2 as uint4
    for (int i = t; i < N / 4; i += RBLK) {
        uint4 v1 = da[i], v2 = db[i];
        s1 += sqrtf(__uint_as_float(v1.x)) + sqrtf(__uint_as_float(v1.y))
            + sqrtf(__uint_as_float(v1.z)) + sqrtf(__uint_as_float(v1.w));
        s2 += sqrtf(__uint_as_float(v2.x)) + sqrtf(__uint_as_float(v2.y))
            + sqrtf(__uint_as_float(v2.z)) + sqrtf(__uint_as_float(v2.w));
    }
    #pragma unroll
    for (int off = 32; off > 0; off >>= 1) {
        s1 += __shfl_down(s1, off, 64);
        s2 += __shfl_down(s2, off, 64);
    }
    int wid = t >> 6, lane = t & 63;
    if (lane == 0) { sh1[wid] = s1; sh2[wid] = s2; }
    __syncthreads();
    if (t == 0) {
        float t1 = 0.0f, t2 = 0.0f;
        #pragma unroll
        for (int w = 0; w < RBLK / 64; ++w) { t1 += sh1[w]; t2 += sh2[w]; }
        int e = curp[0] / subp[0];
        double scale = 10.0 / pow(0.99, (double)e);
        out[0] = (float)((((double)t1 + (double)t2) / (double)N) * 0.5 * scale);
    }
}

// ---------------------------------------------------------------- launch ----
extern "C" void kernel_launch(void* const* d_in, const int* in_sizes, int n_in,
                              void* d_out, int out_size, void* d_ws, size_t ws_size,
                              hipStream_t stream) {
    const float* target = (const float*)d_in[0];   // (1, 8192, 3) f32
    const float* output = (const float*)d_in[1];   // (1, 8192, 3) f32
    const int*   curp   = (const int*)d_in[2];
    const int*   subp   = (const int*)d_in[3];
    float* out = (float*)d_out;

    // ws: float4 P[2N] (256KB) | float Ppk[8N] (256KB) | uint dmin[2N] (64KB)
    float4*   P    = (float4*)d_ws;
    float*    Ppk  = (float*)(P + 2 * N);
    unsigned* dmin = (unsigned*)(Ppk + 8 * N);

    chamfer_prep_kernel<<<2 * N / BLK, BLK, 0, stream>>>(target, output, P, Ppk, dmin);
    chamfer_dist_kernel<<<GRID, BLK, 0, stream>>>(P, (const v2f*)Ppk, dmin);
    chamfer_reduce_kernel<<<1, RBLK, 0, stream>>>(dmin, curp, subp, out);
}